// Round 6
// baseline (928.084 us; speedup 1.0000x reference)
//
#include <hip/hip_runtime.h>
#include <hip/hip_bf16.h>
#include <math.h>

#define BB 16
#define NN 512
#define DD 256
#define KK 12

typedef __bf16 bf16x8 __attribute__((ext_vector_type(8)));
typedef __bf16 bf16x4 __attribute__((ext_vector_type(4)));
typedef float  f32x4  __attribute__((ext_vector_type(4)));

// workspace layout (bytes)
#define WS_WM     0              // wm[b,n] = w*mask_n, f32, 32KB
#define WS_MASKBF 32768          // maskbf[b,n] bf16 0/1, 16KB
#define WS_NODEBF 49152          // node bf16 [B][N][D] (unscaled, self term), 4MB
#define WS_NODET  4243456        // node_t bf16 [B][D][N], scaled by wm, 4MB
#define WS_WKBF   8437760        // Wk bf16 [K][D][D], 1.5MB
#define WS_WSBF   10010624       // Ws bf16 [D][D], 128KB

// ---------------------------------------------------------------- k1: w, all_weight, wm, maskbf, node_bf16
__global__ __launch_bounds__(256) void k1_prep(const float* __restrict__ node,
        const float* __restrict__ Ww, const float* __restrict__ bw,
        const int* __restrict__ node_mask,
        float* __restrict__ wm, __bf16* __restrict__ maskbf,
        __bf16* __restrict__ node_bf, float* __restrict__ all_w) {
    int t = threadIdx.x;
    int lane = t & 63;
    int row = blockIdx.x * 4 + (t >> 6);           // b*N + n
    const float4 nv = *(const float4*)(node + (size_t)row * DD + lane * 4);
    const float4 wv = *(const float4*)(Ww + lane * 4);
    float dot = nv.x*wv.x + nv.y*wv.y + nv.z*wv.z + nv.w*wv.w;
    #pragma unroll
    for (int off = 32; off > 0; off >>= 1) dot += __shfl_xor(dot, off);
    float w = 1.0f / (1.0f + expf(-(dot + bw[0])));
    int mk = node_mask[row];
    if (lane == 0) {
        wm[row]     = w * (float)mk;
        all_w[row]  = w;
        maskbf[row] = (__bf16)(float)mk;
    }
    bf16x4 nb = {(__bf16)nv.x, (__bf16)nv.y, (__bf16)nv.z, (__bf16)nv.w};
    *(bf16x4*)(node_bf + (size_t)row * DD + lane * 4) = nb;
}

// ---------------------------------------------------------------- k1b: Wk, Ws -> bf16
__global__ __launch_bounds__(256) void k1b_convert(const float* __restrict__ Wk,
        const float* __restrict__ Ws, __bf16* __restrict__ Wk_bf, __bf16* __restrict__ Ws_bf) {
    const int KDD = KK * DD * DD;
    int idx = (blockIdx.x * 256 + threadIdx.x) * 4;
    if (idx < KDD) {
        float4 v = *(const float4*)(Wk + idx);
        bf16x4 o = {(__bf16)v.x, (__bf16)v.y, (__bf16)v.z, (__bf16)v.w};
        *(bf16x4*)(Wk_bf + idx) = o;
    } else {
        int j = idx - KDD;
        if (j < DD * DD) {
            float4 v = *(const float4*)(Ws + j);
            bf16x4 o = {(__bf16)v.x, (__bf16)v.y, (__bf16)v.z, (__bf16)v.w};
            *(bf16x4*)(Ws_bf + j) = o;
        }
    }
}

// ---------------------------------------------------------------- k2: node fp32 [B][N][D] -> node_t bf16 [B][D][N] scaled by wm[b,n]
__global__ __launch_bounds__(256) void k2_transpose(const float* __restrict__ node,
        const float* __restrict__ wm, __bf16* __restrict__ dst) {
    __shared__ float tile[64][65];
    int bx = blockIdx.x;
    int b = bx >> 5; int rest = bx & 31; int nt = rest >> 2; int dt = rest & 3;
    int n0 = nt * 64, d0 = dt * 64;
    int t = threadIdx.x;
    #pragma unroll
    for (int i = 0; i < 16; i++) {
        int idx = i * 256 + t;
        int n = idx >> 6, d = idx & 63;
        tile[n][d] = node[((size_t)(b * NN + n0 + n)) * DD + d0 + d];
    }
    __syncthreads();
    #pragma unroll
    for (int i = 0; i < 16; i++) {
        int idx = i * 256 + t;
        int d = idx >> 6, n = idx & 63;
        float w = wm[b * NN + n0 + n];
        dst[((size_t)(b * DD + d0 + d)) * NN + n0 + n] = (__bf16)(tile[n][d] * w);
    }
}

// ---------------------------------------------------------------- k45: fused stageA+stageB
// Block = (b, 16-row m-tile, d-half 128). 256 threads / 4 waves, 4 blocks/CU.
// out[b,m,d] = relu( s[b,m] * Σ_k Σ_e (Σ_n g_k[m,n] wnode[n,e]) Wk[k,d,e] + Σ_e node[m,e] Ws[d,e] + bs[d] )
__global__ __launch_bounds__(256, 4) void k45_fused(const int* __restrict__ graphs,
        const int* __restrict__ node_mask, const __bf16* __restrict__ maskbf,
        const __bf16* __restrict__ node_t, const __bf16* __restrict__ node_bf,
        const __bf16* __restrict__ Wk_bf, const __bf16* __restrict__ Ws_bf,
        const float* __restrict__ bs, float* __restrict__ out) {
    __shared__ __align__(16) __bf16 Abf[16][520];   // 16.6 KB adjacency strip
    __shared__ __align__(16) __bf16 Tk[16][264];    // 8.4 KB per-k T tile
    __shared__ float cntp[4][16];
    __shared__ float sm[16];
    int bx = blockIdx.x;
    int b  = (bx & 7) + 8 * ((bx >> 3) & 1);        // b%8 = XCD id -> b-local L2
    int dh = (bx >> 4) & 1;                          // d-half (stage A duplicated)
    int mt = bx >> 5;                                // 0..31
    int m0 = mt * 16;
    int t = threadIdx.x;
    int lane = t & 63;
    int w = t >> 6;                                  // wave 0..3
    int q = lane >> 4;
    int l16 = lane & 15;
    int esub = w * 64;                               // wave's e-range in stage A (4x16)
    int dsub = dh * 128 + w * 32;                    // wave's d-range in stage B (2x16)

    int rowpar = t >> 7;                             // convert: row parity 0/1
    int ccol   = (t & 127) * 4;                      // convert: column base

    f32x4 accO[2];
    accO[0] = (f32x4){0.f, 0.f, 0.f, 0.f};
    accO[1] = (f32x4){0.f, 0.f, 0.f, 0.f};
    f32x4 accC = (f32x4){0.f, 0.f, 0.f, 0.f};

    // preamble: whole 32 KB strip 0 in flight
    int4 g[8];
    {
        const int4* gb = (const int4*)(graphs + ((size_t)(b * NN + m0)) * NN);
        #pragma unroll
        for (int u = 0; u < 8; u++) g[u] = gb[u * 256 + t];
    }

    #pragma unroll 1
    for (int k = 0; k < KK; k++) {
        // ---- convert strip k (regs -> bf16 LDS), diag cleared
        #pragma unroll
        for (int u = 0; u < 8; u++) {
            int row = u * 2 + rowpar;
            unsigned p0 = (unsigned)g[u].x | ((unsigned)g[u].y << 16);
            unsigned p1 = (unsigned)g[u].z | ((unsigned)g[u].w << 16);
            unsigned drel = (unsigned)(m0 + row - ccol);
            if (drel < 2u)      p0 &= ~(0xFFFFu << (16 * drel));
            else if (drel < 4u) p1 &= ~(0xFFFFu << (16 * (drel - 2)));
            uint2 st; st.x = p0 * 0x3F80u; st.y = p1 * 0x3F80u;
            *(uint2*)&Abf[row][ccol] = st;
        }
        __syncthreads();                             // Abf ready; prev stage-B done with Tk

        // ---- issue next strip (in flight through stage A)
        if (k < KK - 1) {
            const int4* gb = (const int4*)(graphs + ((size_t)(((k + 1) * BB + b) * NN + m0)) * NN);
            #pragma unroll
            for (int u = 0; u < 8; u++) g[u] = gb[u * 256 + t];
        }

        // ---- stage A: T_k[m, e-sub] = Σ_n A[m,n] * wnode[n,e]
        f32x4 accT[4];
        #pragma unroll
        for (int i = 0; i < 4; i++) accT[i] = (f32x4){0.f, 0.f, 0.f, 0.f};
        #pragma unroll
        for (int kk = 0; kk < 16; kk++) {
            int n0c = kk * 32;
            bf16x8 af = *(const bf16x8*)&Abf[l16][n0c + q * 8];
            bf16x8 bfr[4];
            #pragma unroll
            for (int fd = 0; fd < 4; fd++)
                bfr[fd] = *(const bf16x8*)(node_t +
                    ((size_t)(b * DD + esub + fd * 16 + l16)) * NN + n0c + q * 8);
            #pragma unroll
            for (int fd = 0; fd < 4; fd++)
                accT[fd] = __builtin_amdgcn_mfma_f32_16x16x32_bf16(af, bfr[fd], accT[fd], 0, 0, 0);
            // count MFMA: wave w covers chunks 4w..4w+3; D col0 = Σ_n A[m,n]*mask[n]
            if ((kk >> 2) == w) {
                bf16x8 bfm = (bf16x8){0,0,0,0,0,0,0,0};
                if (l16 == 0)
                    bfm = *(const bf16x8*)(maskbf + b * NN + n0c + q * 8);
                accC = __builtin_amdgcn_mfma_f32_16x16x32_bf16(af, bfm, accC, 0, 0, 0);
            }
        }
        // ---- T_k -> LDS bf16 (C/D layout: col=l16, row=q*4+r)
        #pragma unroll
        for (int fd = 0; fd < 4; fd++) {
            int col = esub + fd * 16 + l16;
            #pragma unroll
            for (int r = 0; r < 4; r++)
                Tk[q * 4 + r][col] = (__bf16)accT[fd][r];
        }
        __syncthreads();                             // Tk ready; Abf free for next convert

        // ---- stage B: accO[m, d-sub] += Σ_e T_k[m,e] * Wk[k,d,e]
        #pragma unroll
        for (int ee = 0; ee < 8; ee++) {
            int e0c = ee * 32;
            bf16x8 afT = *(const bf16x8*)&Tk[l16][e0c + q * 8];
            bf16x8 bw2[2];
            #pragma unroll
            for (int fd = 0; fd < 2; fd++)
                bw2[fd] = *(const bf16x8*)(Wk_bf +
                    ((size_t)(k * DD + dsub + fd * 16 + l16)) * DD + e0c + q * 8);
            #pragma unroll
            for (int fd = 0; fd < 2; fd++)
                accO[fd] = __builtin_amdgcn_mfma_f32_16x16x32_bf16(afT, bw2[fd], accO[fd], 0, 0, 0);
        }
    }

    // ---- counts: block-local reduce, s[m] = mask_m / max(1, cnt)
    if (l16 == 0) {
        #pragma unroll
        for (int r = 0; r < 4; r++) cntp[w][q * 4 + r] = accC[r];
    }
    __syncthreads();
    if (t < 16) {
        float c = cntp[0][t] + cntp[1][t] + cntp[2][t] + cntp[3][t];
        int mk = node_mask[b * NN + m0 + t];
        sm[t] = (float)mk / (c >= 0.5f ? c : 1.0f);
    }
    __syncthreads();

    // scale aggregate (linear => exact)
    #pragma unroll
    for (int r = 0; r < 4; r++) {
        float s = sm[q * 4 + r];
        accO[0][r] *= s;
        accO[1][r] *= s;
    }

    // ---- self: accO += node @ Ws^T
    #pragma unroll
    for (int ee = 0; ee < 8; ee++) {
        int e0c = ee * 32;
        bf16x8 afS = *(const bf16x8*)(node_bf +
            ((size_t)(b * NN + m0 + l16)) * DD + e0c + q * 8);
        bf16x8 bwS[2];
        #pragma unroll
        for (int fd = 0; fd < 2; fd++)
            bwS[fd] = *(const bf16x8*)(Ws_bf +
                ((size_t)(dsub + fd * 16 + l16)) * DD + e0c + q * 8);
        #pragma unroll
        for (int fd = 0; fd < 2; fd++)
            accO[fd] = __builtin_amdgcn_mfma_f32_16x16x32_bf16(afS, bwS[fd], accO[fd], 0, 0, 0);
    }

    // ---- epilogue: + bs, relu, store f32
    #pragma unroll
    for (int fd = 0; fd < 2; fd++) {
        int d = dsub + fd * 16 + l16;
        float bsv = bs[d];
        #pragma unroll
        for (int r = 0; r < 4; r++) {
            int m = m0 + q * 4 + r;
            float v = accO[fd][r] + bsv;
            out[((size_t)(b * NN + m)) * DD + d] = fmaxf(v, 0.0f);
        }
    }
}

// ----------------------------------------------------------------
extern "C" void kernel_launch(void* const* d_in, const int* in_sizes, int n_in,
                              void* d_out, int out_size, void* d_ws, size_t ws_size,
                              hipStream_t stream) {
    const float* node      = (const float*)d_in[0];
    const float* Ww        = (const float*)d_in[1];
    const float* bw        = (const float*)d_in[2];
    const float* Ws        = (const float*)d_in[3];
    const float* bs        = (const float*)d_in[4];
    const float* Wk        = (const float*)d_in[5];
    const int*   node_mask = (const int*)d_in[6];
    const int*   graphs    = (const int*)d_in[7];
    float* out   = (float*)d_out;
    float* all_w = out + (size_t)BB * NN * DD;

    char* ws = (char*)d_ws;
    float*  wm      = (float*)(ws + WS_WM);
    __bf16* maskbf  = (__bf16*)(ws + WS_MASKBF);
    __bf16* node_bf = (__bf16*)(ws + WS_NODEBF);
    __bf16* node_t  = (__bf16*)(ws + WS_NODET);
    __bf16* Wk_bf   = (__bf16*)(ws + WS_WKBF);
    __bf16* Ws_bf   = (__bf16*)(ws + WS_WSBF);

    k1_prep    <<<2048, 256, 0, stream>>>(node, Ww, bw, node_mask, wm, maskbf, node_bf, all_w);
    k1b_convert<<< 832, 256, 0, stream>>>(Wk, Ws, Wk_bf, Ws_bf);
    k2_transpose<<<512, 256, 0, stream>>>(node, wm, node_t);
    k45_fused  <<<1024, 256, 0, stream>>>(graphs, node_mask, maskbf, node_t, node_bf,
                                          Wk_bf, Ws_bf, bs, out);
}

// Round 7
// 518.180 us; speedup vs baseline: 1.7910x; 1.7910x over previous
//
#include <hip/hip_runtime.h>
#include <hip/hip_bf16.h>
#include <math.h>

#define BB 16
#define NN 512
#define DD 256
#define KK 12

typedef __bf16 bf16x8 __attribute__((ext_vector_type(8)));
typedef __bf16 bf16x4 __attribute__((ext_vector_type(4)));
typedef float  f32x4  __attribute__((ext_vector_type(4)));

// workspace layout (bytes)
#define WS_WM     0              // wm[b,n] = w*mask_n, f32, 32KB
#define WS_MASKBF 32768          // maskbf[b,n] bf16 0/1, 16KB
#define WS_NODEBF 49152          // node bf16 [B][N][D] (unscaled, self term), 4MB
#define WS_NODET  4243456        // node_t bf16 [B][D][N], scaled by wm, 4MB
#define WS_WKBF   8437760        // Wk bf16 [K][D][D], 1.5MB
#define WS_WSBF   10010624       // Ws bf16 [D][D], 128KB

// ---------------------------------------------------------------- k1: w, all_weight, wm, maskbf, node_bf16
__global__ __launch_bounds__(256) void k1_prep(const float* __restrict__ node,
        const float* __restrict__ Ww, const float* __restrict__ bw,
        const int* __restrict__ node_mask,
        float* __restrict__ wm, __bf16* __restrict__ maskbf,
        __bf16* __restrict__ node_bf, float* __restrict__ all_w) {
    int t = threadIdx.x;
    int lane = t & 63;
    int row = blockIdx.x * 4 + (t >> 6);           // b*N + n
    const float4 nv = *(const float4*)(node + (size_t)row * DD + lane * 4);
    const float4 wv = *(const float4*)(Ww + lane * 4);
    float dot = nv.x*wv.x + nv.y*wv.y + nv.z*wv.z + nv.w*wv.w;
    #pragma unroll
    for (int off = 32; off > 0; off >>= 1) dot += __shfl_xor(dot, off);
    float w = 1.0f / (1.0f + expf(-(dot + bw[0])));
    int mk = node_mask[row];
    if (lane == 0) {
        wm[row]     = w * (float)mk;
        all_w[row]  = w;
        maskbf[row] = (__bf16)(float)mk;
    }
    bf16x4 nb = {(__bf16)nv.x, (__bf16)nv.y, (__bf16)nv.z, (__bf16)nv.w};
    *(bf16x4*)(node_bf + (size_t)row * DD + lane * 4) = nb;
}

// ---------------------------------------------------------------- k1b: Wk, Ws -> bf16
__global__ __launch_bounds__(256) void k1b_convert(const float* __restrict__ Wk,
        const float* __restrict__ Ws, __bf16* __restrict__ Wk_bf, __bf16* __restrict__ Ws_bf) {
    const int KDD = KK * DD * DD;
    int idx = (blockIdx.x * 256 + threadIdx.x) * 4;
    if (idx < KDD) {
        float4 v = *(const float4*)(Wk + idx);
        bf16x4 o = {(__bf16)v.x, (__bf16)v.y, (__bf16)v.z, (__bf16)v.w};
        *(bf16x4*)(Wk_bf + idx) = o;
    } else {
        int j = idx - KDD;
        if (j < DD * DD) {
            float4 v = *(const float4*)(Ws + j);
            bf16x4 o = {(__bf16)v.x, (__bf16)v.y, (__bf16)v.z, (__bf16)v.w};
            *(bf16x4*)(Ws_bf + j) = o;
        }
    }
}

// ---------------------------------------------------------------- k2: node fp32 [B][N][D] -> node_t bf16 [B][D][N] scaled by wm[b,n]
__global__ __launch_bounds__(256) void k2_transpose(const float* __restrict__ node,
        const float* __restrict__ wm, __bf16* __restrict__ dst) {
    __shared__ float tile[64][65];
    int bx = blockIdx.x;
    int b = bx >> 5; int rest = bx & 31; int nt = rest >> 2; int dt = rest & 3;
    int n0 = nt * 64, d0 = dt * 64;
    int t = threadIdx.x;
    #pragma unroll
    for (int i = 0; i < 16; i++) {
        int idx = i * 256 + t;
        int n = idx >> 6, d = idx & 63;
        tile[n][d] = node[((size_t)(b * NN + n0 + n)) * DD + d0 + d];
    }
    __syncthreads();
    #pragma unroll
    for (int i = 0; i < 16; i++) {
        int idx = i * 256 + t;
        int d = idx >> 6, n = idx & 63;
        float w = wm[b * NN + n0 + n];
        dst[((size_t)(b * DD + d0 + d)) * NN + n0 + n] = (__bf16)(tile[n][d] * w);
    }
}

// ---------------------------------------------------------------- k45: fused stageA+stageB
// Block = (b, 16-row m-tile, d-half 128). 256 threads / 4 waves.
// NOTE: plain launch_bounds(256) — R6's (256,4) min-waves bound forced a 64-VGPR
// allocation and ~550 MB of scratch spill traffic (VGPR_Count=64, WRITE_SIZE=284MB).
__global__ __launch_bounds__(256) void k45_fused(const int* __restrict__ graphs,
        const int* __restrict__ node_mask, const __bf16* __restrict__ maskbf,
        const __bf16* __restrict__ node_t, const __bf16* __restrict__ node_bf,
        const __bf16* __restrict__ Wk_bf, const __bf16* __restrict__ Ws_bf,
        const float* __restrict__ bs, float* __restrict__ out) {
    __shared__ __align__(16) __bf16 Abf[16][520];   // 16.6 KB adjacency strip
    __shared__ __align__(16) __bf16 Tk[16][264];    // 8.4 KB per-k T tile
    __shared__ float cntp[4][16];
    __shared__ float sm[16];
    int bx = blockIdx.x;
    int b  = (bx & 7) + 8 * ((bx >> 3) & 1);        // b%8 = XCD id -> b-local L2
    int dh = (bx >> 4) & 1;                          // d-half (stage A duplicated)
    int mt = bx >> 5;                                // 0..31
    int m0 = mt * 16;
    int t = threadIdx.x;
    int lane = t & 63;
    int w = t >> 6;                                  // wave 0..3
    int q = lane >> 4;
    int l16 = lane & 15;
    int esub = w * 64;                               // wave's e-range in stage A (4x16)
    int dsub = dh * 128 + w * 32;                    // wave's d-range in stage B (2x16)

    int rowpar = t >> 7;                             // convert: row parity 0/1
    int ccol   = (t & 127) * 4;                      // convert: column base

    f32x4 accO[2];
    accO[0] = (f32x4){0.f, 0.f, 0.f, 0.f};
    accO[1] = (f32x4){0.f, 0.f, 0.f, 0.f};
    f32x4 accC = (f32x4){0.f, 0.f, 0.f, 0.f};

    // preamble: whole 32 KB strip 0 in flight
    int4 g[8];
    {
        const int4* gb = (const int4*)(graphs + ((size_t)(b * NN + m0)) * NN);
        #pragma unroll
        for (int u = 0; u < 8; u++) g[u] = gb[u * 256 + t];
    }

    #pragma unroll 1
    for (int k = 0; k < KK; k++) {
        // ---- convert strip k (regs -> bf16 LDS), diag cleared
        #pragma unroll
        for (int u = 0; u < 8; u++) {
            int row = u * 2 + rowpar;
            unsigned p0 = (unsigned)g[u].x | ((unsigned)g[u].y << 16);
            unsigned p1 = (unsigned)g[u].z | ((unsigned)g[u].w << 16);
            unsigned drel = (unsigned)(m0 + row - ccol);
            if (drel < 2u)      p0 &= ~(0xFFFFu << (16 * drel));
            else if (drel < 4u) p1 &= ~(0xFFFFu << (16 * (drel - 2)));
            uint2 st; st.x = p0 * 0x3F80u; st.y = p1 * 0x3F80u;
            *(uint2*)&Abf[row][ccol] = st;
        }
        __syncthreads();                             // Abf ready; prev stage-B done with Tk

        // ---- issue next strip (in flight through stage A)
        if (k < KK - 1) {
            const int4* gb = (const int4*)(graphs + ((size_t)(((k + 1) * BB + b) * NN + m0)) * NN);
            #pragma unroll
            for (int u = 0; u < 8; u++) g[u] = gb[u * 256 + t];
        }

        // ---- stage A: T_k[m, e-sub] = Σ_n A[m,n] * wnode[n,e]
        f32x4 accT[4];
        #pragma unroll
        for (int i = 0; i < 4; i++) accT[i] = (f32x4){0.f, 0.f, 0.f, 0.f};
        #pragma unroll
        for (int kk = 0; kk < 16; kk++) {
            int n0c = kk * 32;
            bf16x8 af = *(const bf16x8*)&Abf[l16][n0c + q * 8];
            bf16x8 bfr[4];
            #pragma unroll
            for (int fd = 0; fd < 4; fd++)
                bfr[fd] = *(const bf16x8*)(node_t +
                    ((size_t)(b * DD + esub + fd * 16 + l16)) * NN + n0c + q * 8);
            #pragma unroll
            for (int fd = 0; fd < 4; fd++)
                accT[fd] = __builtin_amdgcn_mfma_f32_16x16x32_bf16(af, bfr[fd], accT[fd], 0, 0, 0);
            // count MFMA: wave w covers chunks 4w..4w+3; D col0 = Σ_n A[m,n]*mask[n]
            if ((kk >> 2) == w) {
                bf16x8 bfm = (bf16x8){0,0,0,0,0,0,0,0};
                if (l16 == 0)
                    bfm = *(const bf16x8*)(maskbf + b * NN + n0c + q * 8);
                accC = __builtin_amdgcn_mfma_f32_16x16x32_bf16(af, bfm, accC, 0, 0, 0);
            }
        }
        // ---- T_k -> LDS bf16 (C/D layout: col=l16, row=q*4+r)
        #pragma unroll
        for (int fd = 0; fd < 4; fd++) {
            int col = esub + fd * 16 + l16;
            #pragma unroll
            for (int r = 0; r < 4; r++)
                Tk[q * 4 + r][col] = (__bf16)accT[fd][r];
        }
        __syncthreads();                             // Tk ready; Abf free for next convert

        // ---- stage B: accO[m, d-sub] += Σ_e T_k[m,e] * Wk[k,d,e]
        #pragma unroll
        for (int ee = 0; ee < 8; ee++) {
            int e0c = ee * 32;
            bf16x8 afT = *(const bf16x8*)&Tk[l16][e0c + q * 8];
            bf16x8 bw2[2];
            #pragma unroll
            for (int fd = 0; fd < 2; fd++)
                bw2[fd] = *(const bf16x8*)(Wk_bf +
                    ((size_t)(k * DD + dsub + fd * 16 + l16)) * DD + e0c + q * 8);
            #pragma unroll
            for (int fd = 0; fd < 2; fd++)
                accO[fd] = __builtin_amdgcn_mfma_f32_16x16x32_bf16(afT, bw2[fd], accO[fd], 0, 0, 0);
        }
    }

    // ---- counts: block-local reduce, s[m] = mask_m / max(1, cnt)
    if (l16 == 0) {
        #pragma unroll
        for (int r = 0; r < 4; r++) cntp[w][q * 4 + r] = accC[r];
    }
    __syncthreads();
    if (t < 16) {
        float c = cntp[0][t] + cntp[1][t] + cntp[2][t] + cntp[3][t];
        int mk = node_mask[b * NN + m0 + t];
        sm[t] = (float)mk / (c >= 0.5f ? c : 1.0f);
    }
    __syncthreads();

    // scale aggregate (linear => exact)
    #pragma unroll
    for (int r = 0; r < 4; r++) {
        float s = sm[q * 4 + r];
        accO[0][r] *= s;
        accO[1][r] *= s;
    }

    // ---- self: accO += node @ Ws^T
    #pragma unroll
    for (int ee = 0; ee < 8; ee++) {
        int e0c = ee * 32;
        bf16x8 afS = *(const bf16x8*)(node_bf +
            ((size_t)(b * NN + m0 + l16)) * DD + e0c + q * 8);
        bf16x8 bwS[2];
        #pragma unroll
        for (int fd = 0; fd < 2; fd++)
            bwS[fd] = *(const bf16x8*)(Ws_bf +
                ((size_t)(dsub + fd * 16 + l16)) * DD + e0c + q * 8);
        #pragma unroll
        for (int fd = 0; fd < 2; fd++)
            accO[fd] = __builtin_amdgcn_mfma_f32_16x16x32_bf16(afS, bwS[fd], accO[fd], 0, 0, 0);
    }

    // ---- epilogue: + bs, relu, store f32
    #pragma unroll
    for (int fd = 0; fd < 2; fd++) {
        int d = dsub + fd * 16 + l16;
        float bsv = bs[d];
        #pragma unroll
        for (int r = 0; r < 4; r++) {
            int m = m0 + q * 4 + r;
            float v = accO[fd][r] + bsv;
            out[((size_t)(b * NN + m)) * DD + d] = fmaxf(v, 0.0f);
        }
    }
}

// ----------------------------------------------------------------
extern "C" void kernel_launch(void* const* d_in, const int* in_sizes, int n_in,
                              void* d_out, int out_size, void* d_ws, size_t ws_size,
                              hipStream_t stream) {
    const float* node      = (const float*)d_in[0];
    const float* Ww        = (const float*)d_in[1];
    const float* bw        = (const float*)d_in[2];
    const float* Ws        = (const float*)d_in[3];
    const float* bs        = (const float*)d_in[4];
    const float* Wk        = (const float*)d_in[5];
    const int*   node_mask = (const int*)d_in[6];
    const int*   graphs    = (const int*)d_in[7];
    float* out   = (float*)d_out;
    float* all_w = out + (size_t)BB * NN * DD;

    char* ws = (char*)d_ws;
    float*  wm      = (float*)(ws + WS_WM);
    __bf16* maskbf  = (__bf16*)(ws + WS_MASKBF);
    __bf16* node_bf = (__bf16*)(ws + WS_NODEBF);
    __bf16* node_t  = (__bf16*)(ws + WS_NODET);
    __bf16* Wk_bf   = (__bf16*)(ws + WS_WKBF);
    __bf16* Ws_bf   = (__bf16*)(ws + WS_WSBF);

    k1_prep    <<<2048, 256, 0, stream>>>(node, Ww, bw, node_mask, wm, maskbf, node_bf, all_w);
    k1b_convert<<< 832, 256, 0, stream>>>(Wk, Ws, Wk_bf, Ws_bf);
    k2_transpose<<<512, 256, 0, stream>>>(node, wm, node_t);
    k45_fused  <<<1024, 256, 0, stream>>>(graphs, node_mask, maskbf, node_t, node_bf,
                                          Wk_bf, Ws_bf, bs, out);
}

// Round 8
// 373.610 us; speedup vs baseline: 2.4841x; 1.3870x over previous
//
#include <hip/hip_runtime.h>
#include <hip/hip_bf16.h>
#include <math.h>

#define BB 16
#define NN 512
#define DD 256
#define KK 12

typedef __bf16 bf16x8 __attribute__((ext_vector_type(8)));
typedef __bf16 bf16x4 __attribute__((ext_vector_type(4)));
typedef float  f32x4  __attribute__((ext_vector_type(4)));

// workspace layout (bytes)
#define WS_WM     0              // wm[b,n] f32, 32KB
#define WS_NCNT   32768          // ncnt[b,m] int32 (atomic), 32KB
#define WS_MASKBF 65536          // maskbf[b,n] bf16 0/1, 16KB
#define WS_NODEBF 81920          // node bf16 [B][N][D], 4MB
#define WS_NODET  4276224        // node_t bf16 [B][D][N] scaled by wm, 4MB
#define WS_WKBF   8470528        // Wk bf16 [K][D][D], 1.5MB
#define WS_WSBF   10043392       // Ws bf16 [D][D], 128KB
#define WS_AGG    10174464       // Agg f32 [2][B][N][D] partial aggregates, 64MB

// ---------------------------------------------------------------- k1: w, all_weight, wm, maskbf, node_bf16
__global__ __launch_bounds__(256) void k1_prep(const float* __restrict__ node,
        const float* __restrict__ Ww, const float* __restrict__ bw,
        const int* __restrict__ node_mask,
        float* __restrict__ wm, __bf16* __restrict__ maskbf,
        __bf16* __restrict__ node_bf, float* __restrict__ all_w) {
    int t = threadIdx.x;
    int lane = t & 63;
    int row = blockIdx.x * 4 + (t >> 6);           // b*N + n
    const float4 nv = *(const float4*)(node + (size_t)row * DD + lane * 4);
    const float4 wv = *(const float4*)(Ww + lane * 4);
    float dot = nv.x*wv.x + nv.y*wv.y + nv.z*wv.z + nv.w*wv.w;
    #pragma unroll
    for (int off = 32; off > 0; off >>= 1) dot += __shfl_xor(dot, off);
    float w = 1.0f / (1.0f + expf(-(dot + bw[0])));
    int mk = node_mask[row];
    if (lane == 0) {
        wm[row]     = w * (float)mk;
        all_w[row]  = w;
        maskbf[row] = (__bf16)(float)mk;
    }
    bf16x4 nb = {(__bf16)nv.x, (__bf16)nv.y, (__bf16)nv.z, (__bf16)nv.w};
    *(bf16x4*)(node_bf + (size_t)row * DD + lane * 4) = nb;
}

// ---------------------------------------------------------------- k1b: Wk, Ws -> bf16
__global__ __launch_bounds__(256) void k1b_convert(const float* __restrict__ Wk,
        const float* __restrict__ Ws, __bf16* __restrict__ Wk_bf, __bf16* __restrict__ Ws_bf) {
    const int KDD = KK * DD * DD;
    int idx = (blockIdx.x * 256 + threadIdx.x) * 4;
    if (idx < KDD) {
        float4 v = *(const float4*)(Wk + idx);
        bf16x4 o = {(__bf16)v.x, (__bf16)v.y, (__bf16)v.z, (__bf16)v.w};
        *(bf16x4*)(Wk_bf + idx) = o;
    } else {
        int j = idx - KDD;
        if (j < DD * DD) {
            float4 v = *(const float4*)(Ws + j);
            bf16x4 o = {(__bf16)v.x, (__bf16)v.y, (__bf16)v.z, (__bf16)v.w};
            *(bf16x4*)(Ws_bf + j) = o;
        }
    }
}

// ---------------------------------------------------------------- k2: node fp32 [B][N][D] -> node_t bf16 [B][D][N] scaled by wm[b,n]
__global__ __launch_bounds__(256) void k2_transpose(const float* __restrict__ node,
        const float* __restrict__ wm, __bf16* __restrict__ dst) {
    __shared__ float tile[64][65];
    int bx = blockIdx.x;
    int b = bx >> 5; int rest = bx & 31; int nt = rest >> 2; int dt = rest & 3;
    int n0 = nt * 64, d0 = dt * 64;
    int t = threadIdx.x;
    #pragma unroll
    for (int i = 0; i < 16; i++) {
        int idx = i * 256 + t;
        int n = idx >> 6, d = idx & 63;
        tile[n][d] = node[((size_t)(b * NN + n0 + n)) * DD + d0 + d];
    }
    __syncthreads();
    #pragma unroll
    for (int i = 0; i < 16; i++) {
        int idx = i * 256 + t;
        int d = idx >> 6, n = idx & 63;
        float w = wm[b * NN + n0 + n];
        dst[((size_t)(b * DD + d0 + d)) * NN + n0 + n] = (__bf16)(tile[n][d] * w);
    }
}

// ---------------------------------------------------------------- k45: fused stageA+stageB, k-split partial
// Block = (b, 32-row m-tile, k-half). 512 threads / 8 waves, R5 shape (traffic-optimal),
// grid 512 -> target 2 blocks/CU. Writes UNSCALED partial aggregate to Agg[kh]; counts via atomicAdd.
__global__ __launch_bounds__(512, 2) void k45_partial(const int* __restrict__ graphs,
        const __bf16* __restrict__ maskbf, const __bf16* __restrict__ node_t,
        const __bf16* __restrict__ Wk_bf, float* __restrict__ Agg, int* __restrict__ ncnt) {
    __shared__ __align__(16) __bf16 Abf[32][520];   // 33.3 KB adjacency strip
    __shared__ __align__(16) __bf16 Tk[32][264];    // 16.9 KB per-k T tile
    __shared__ float cntp[8][32];
    int bx = blockIdx.x;
    int b  = (bx & 7) + 8 * ((bx >> 3) & 1);        // b%8 = XCD id
    int kh = (bx >> 4) & 1;                          // k-half: {0..5} or {6..11}
    int mt = bx >> 5;                                // 0..15
    int m0 = mt * 32;
    int t = threadIdx.x;
    int lane = t & 63;
    int w = t >> 6;                                  // wave 0..7
    int q = lane >> 4;
    int l16 = lane & 15;
    int esub = w * 32;                               // wave's e-range in stage A
    int dsub = w * 32;                               // wave's d-range in stage B

    int crow = t >> 7;                               // convert: row group 0..3
    int ccol = (t & 127) * 4;                        // convert: column base

    f32x4 accO[2][2];
    #pragma unroll
    for (int i = 0; i < 2; i++)
        #pragma unroll
        for (int j = 0; j < 2; j++) accO[i][j] = (f32x4){0.f, 0.f, 0.f, 0.f};
    f32x4 accC[2];
    accC[0] = (f32x4){0.f, 0.f, 0.f, 0.f};
    accC[1] = (f32x4){0.f, 0.f, 0.f, 0.f};

    // preamble: strip kh*6 fully in flight (64 KB/block)
    int4 g[8];
    {
        const int4* gb = (const int4*)(graphs + ((size_t)((kh * 6 * BB + b) * NN + m0)) * NN);
        #pragma unroll
        for (int u = 0; u < 8; u++) g[u] = gb[u * 512 + t];
    }

    #pragma unroll 1
    for (int kc = 0; kc < 6; kc++) {
        int k = kh * 6 + kc;
        // ---- convert strip (regs -> bf16 LDS), diag cleared
        #pragma unroll
        for (int u = 0; u < 8; u++) {
            int row = u * 4 + crow;
            unsigned p0 = (unsigned)g[u].x | ((unsigned)g[u].y << 16);
            unsigned p1 = (unsigned)g[u].z | ((unsigned)g[u].w << 16);
            unsigned drel = (unsigned)(m0 + row - ccol);
            if (drel < 2u)      p0 &= ~(0xFFFFu << (16 * drel));
            else if (drel < 4u) p1 &= ~(0xFFFFu << (16 * (drel - 2)));
            uint2 st; st.x = p0 * 0x3F80u; st.y = p1 * 0x3F80u;
            *(uint2*)&Abf[row][ccol] = st;
        }
        __syncthreads();                             // Abf ready; prev stage-B done with Tk

        // ---- issue next strip (in flight through stage A)
        if (kc < 5) {
            const int4* gb = (const int4*)(graphs + ((size_t)(((k + 1) * BB + b) * NN + m0)) * NN);
            #pragma unroll
            for (int u = 0; u < 8; u++) g[u] = gb[u * 512 + t];
        }

        // ---- stage A: T_k[m, e-sub] = Σ_n A[m,n] * wnode[n,e]
        f32x4 accT[2][2];
        #pragma unroll
        for (int i = 0; i < 2; i++)
            #pragma unroll
            for (int j = 0; j < 2; j++) accT[i][j] = (f32x4){0.f, 0.f, 0.f, 0.f};
        #pragma unroll
        for (int kk = 0; kk < 16; kk++) {
            int n0c = kk * 32;
            bf16x8 af[2], bfr[2];
            #pragma unroll
            for (int fm = 0; fm < 2; fm++)
                af[fm] = *(const bf16x8*)&Abf[fm * 16 + l16][n0c + q * 8];
            #pragma unroll
            for (int fd = 0; fd < 2; fd++)
                bfr[fd] = *(const bf16x8*)(node_t +
                    ((size_t)(b * DD + esub + fd * 16 + l16)) * NN + n0c + q * 8);
            #pragma unroll
            for (int fm = 0; fm < 2; fm++)
                #pragma unroll
                for (int fd = 0; fd < 2; fd++)
                    accT[fm][fd] = __builtin_amdgcn_mfma_f32_16x16x32_bf16(
                        af[fm], bfr[fd], accT[fm][fd], 0, 0, 0);
            // count MFMA: wave w covers chunks {2w, 2w+1}
            if ((kk >> 1) == w) {
                bf16x8 bfm = (bf16x8){0,0,0,0,0,0,0,0};
                if (l16 == 0)
                    bfm = *(const bf16x8*)(maskbf + b * NN + n0c + q * 8);
                accC[0] = __builtin_amdgcn_mfma_f32_16x16x32_bf16(af[0], bfm, accC[0], 0, 0, 0);
                accC[1] = __builtin_amdgcn_mfma_f32_16x16x32_bf16(af[1], bfm, accC[1], 0, 0, 0);
            }
        }
        // ---- T_k -> LDS bf16 (C/D layout: col=l16, row=q*4+r)
        #pragma unroll
        for (int fm = 0; fm < 2; fm++)
            #pragma unroll
            for (int fd = 0; fd < 2; fd++) {
                int col = esub + fd * 16 + l16;
                #pragma unroll
                for (int r = 0; r < 4; r++)
                    Tk[fm * 16 + q * 4 + r][col] = (__bf16)accT[fm][fd][r];
            }
        __syncthreads();                             // Tk ready; Abf free for next convert

        // ---- stage B: accO += Σ_e T_k[m,e] * Wk[k,d,e]
        #pragma unroll
        for (int ee = 0; ee < 8; ee++) {
            int e0c = ee * 32;
            bf16x8 afT[2], bw2[2];
            #pragma unroll
            for (int fm = 0; fm < 2; fm++)
                afT[fm] = *(const bf16x8*)&Tk[fm * 16 + l16][e0c + q * 8];
            #pragma unroll
            for (int fd = 0; fd < 2; fd++)
                bw2[fd] = *(const bf16x8*)(Wk_bf +
                    ((size_t)(k * DD + dsub + fd * 16 + l16)) * DD + e0c + q * 8);
            #pragma unroll
            for (int fm = 0; fm < 2; fm++)
                #pragma unroll
                for (int fd = 0; fd < 2; fd++)
                    accO[fm][fd] = __builtin_amdgcn_mfma_f32_16x16x32_bf16(
                        afT[fm], bw2[fd], accO[fm][fd], 0, 0, 0);
        }
    }

    // ---- counts: block-local reduce, one atomic per row
    if (l16 == 0) {
        #pragma unroll
        for (int fm = 0; fm < 2; fm++)
            #pragma unroll
            for (int r = 0; r < 4; r++)
                cntp[w][fm * 16 + q * 4 + r] = accC[fm][r];
    }
    __syncthreads();
    if (t < 32) {
        float c = 0.0f;
        #pragma unroll
        for (int w8 = 0; w8 < 8; w8++) c += cntp[w8][t];
        atomicAdd(&ncnt[b * NN + m0 + t], (int)(c + 0.5f));
    }

    // ---- store unscaled partial aggregate f32
    float* Ah = Agg + (size_t)kh * BB * NN * DD;
    #pragma unroll
    for (int fm = 0; fm < 2; fm++)
        #pragma unroll
        for (int fd = 0; fd < 2; fd++) {
            int d = dsub + fd * 16 + l16;
            #pragma unroll
            for (int r = 0; r < 4; r++) {
                int m = m0 + fm * 16 + q * 4 + r;
                Ah[((size_t)(b * NN + m)) * DD + d] = accO[fm][fd][r];
            }
        }
}

// ---------------------------------------------------------------- k6: epilogue
// out = relu( s[b,m]*(Agg0+Agg1) + node @ Ws^T + bs )
__global__ __launch_bounds__(256) void k6_epilogue(const float* __restrict__ Agg,
        const __bf16* __restrict__ node_bf, const __bf16* __restrict__ Ws_bf,
        const float* __restrict__ bs, const int* __restrict__ ncnt,
        const int* __restrict__ node_mask, float* __restrict__ out) {
    __shared__ float sm[16];
    int bx = blockIdx.x;
    int b = bx & 15;
    int mt = bx >> 4;                                // 0..31
    int m0 = mt * 16;
    int t = threadIdx.x;
    int lane = t & 63;
    int w = t >> 6;
    int q = lane >> 4;
    int l16 = lane & 15;
    int dsub = w * 64;

    if (t < 16) {
        int c = ncnt[b * NN + m0 + t];
        int mk = node_mask[b * NN + m0 + t];
        sm[t] = (float)mk / (float)(c >= 1 ? c : 1);
    }

    // self term via MFMA
    f32x4 accS[4];
    #pragma unroll
    for (int i = 0; i < 4; i++) accS[i] = (f32x4){0.f, 0.f, 0.f, 0.f};
    #pragma unroll
    for (int ee = 0; ee < 8; ee++) {
        int e0c = ee * 32;
        bf16x8 afS = *(const bf16x8*)(node_bf +
            ((size_t)(b * NN + m0 + l16)) * DD + e0c + q * 8);
        bf16x8 bwS[4];
        #pragma unroll
        for (int fd = 0; fd < 4; fd++)
            bwS[fd] = *(const bf16x8*)(Ws_bf +
                ((size_t)(dsub + fd * 16 + l16)) * DD + e0c + q * 8);
        #pragma unroll
        for (int fd = 0; fd < 4; fd++)
            accS[fd] = __builtin_amdgcn_mfma_f32_16x16x32_bf16(afS, bwS[fd], accS[fd], 0, 0, 0);
    }
    __syncthreads();

    const float* A0 = Agg;
    const float* A1 = Agg + (size_t)BB * NN * DD;
    #pragma unroll
    for (int fd = 0; fd < 4; fd++) {
        int d = dsub + fd * 16 + l16;
        float bsv = bs[d];
        #pragma unroll
        for (int r = 0; r < 4; r++) {
            int m = m0 + q * 4 + r;
            size_t idx = ((size_t)(b * NN + m)) * DD + d;
            float v = sm[q * 4 + r] * (A0[idx] + A1[idx]) + accS[fd][r] + bsv;
            out[idx] = fmaxf(v, 0.0f);
        }
    }
}

// ----------------------------------------------------------------
extern "C" void kernel_launch(void* const* d_in, const int* in_sizes, int n_in,
                              void* d_out, int out_size, void* d_ws, size_t ws_size,
                              hipStream_t stream) {
    const float* node      = (const float*)d_in[0];
    const float* Ww        = (const float*)d_in[1];
    const float* bw        = (const float*)d_in[2];
    const float* Ws        = (const float*)d_in[3];
    const float* bs        = (const float*)d_in[4];
    const float* Wk        = (const float*)d_in[5];
    const int*   node_mask = (const int*)d_in[6];
    const int*   graphs    = (const int*)d_in[7];
    float* out   = (float*)d_out;
    float* all_w = out + (size_t)BB * NN * DD;

    char* ws = (char*)d_ws;
    float*  wm      = (float*)(ws + WS_WM);
    int*    ncnt    = (int*)(ws + WS_NCNT);
    __bf16* maskbf  = (__bf16*)(ws + WS_MASKBF);
    __bf16* node_bf = (__bf16*)(ws + WS_NODEBF);
    __bf16* node_t  = (__bf16*)(ws + WS_NODET);
    __bf16* Wk_bf   = (__bf16*)(ws + WS_WKBF);
    __bf16* Ws_bf   = (__bf16*)(ws + WS_WSBF);
    float*  Agg     = (float*)(ws + WS_AGG);

    hipMemsetAsync(ncnt, 0, BB * NN * sizeof(int), stream);
    k1_prep    <<<2048, 256, 0, stream>>>(node, Ww, bw, node_mask, wm, maskbf, node_bf, all_w);
    k1b_convert<<< 832, 256, 0, stream>>>(Wk, Ws, Wk_bf, Ws_bf);
    k2_transpose<<<512, 256, 0, stream>>>(node, wm, node_t);
    k45_partial<<< 512, 512, 0, stream>>>(graphs, maskbf, node_t, Wk_bf, Agg, ncnt);
    k6_epilogue<<< 512, 256, 0, stream>>>(Agg, node_bf, Ws_bf, bs, ncnt, node_mask, out);
}